// Round 13
// baseline (248.098 us; speedup 1.0000x reference)
//
#include <hip/hip_runtime.h>
#include <math.h>

#define NQ 20000
#define MS 20000
#define HN 32
#define CH 128
#define DH 64
#define KTOT 20
#define KMINI 7
#define EPSN 1e-5f
#define NKT 80
#define KT_Y1 28

// workspace layout (float units)
#define OFF_ROWSUM 0
#define OFF_Y1     20480
#define OFF_Y2     (OFF_Y1 + NQ*DH)
#define OFF_SEGSUM (OFF_Y2 + NQ*DH)           // 512, zeroed
#define OFF_BNSUM  (OFF_SEGSUM + 512)         // 128, zeroed
#define OFF_BNSQ   (OFF_BNSUM + 128)          // 128, zeroed
#define OFF_OUTPRE (OFF_BNSQ + 128)           // NQ*CH
#define OFF_WSWZ   (OFF_OUTPRE + NQ*CH)       // 327680 ushort
#define OFF_CFRAG  (OFF_WSWZ + 163840)        // 16384 ushort
#define OFF_XBF    (OFF_CFRAG + 8192)         // NQ*CH ushort
#define TOT_FLOATS (OFF_XBF + NQ*CH/2)

// Pt LDS pitches (elements)
#define PK 40                 // k-row stride
#define PQ 840                // query stride (21*40)

typedef __attribute__((ext_vector_type(8))) short bf16x8;
typedef __attribute__((ext_vector_type(4))) float f32x4;
typedef __attribute__((ext_vector_type(4))) unsigned short us4;
typedef __attribute__((ext_vector_type(8))) unsigned short us8;

static __device__ inline unsigned short f2bf(float f) {
    unsigned int u = __float_as_uint(f);
    unsigned int r = (u + 0x7fffu + ((u >> 16) & 1u)) >> 16;
    return (unsigned short)r;
}

// --- kernel P: rowsum+x_bf (<1250) | weight swizzle (<2530) | C frags (rest) --
__global__ __launch_bounds__(256) void k_prep(
    const float* __restrict__ x, float* __restrict__ rowsum,
    const float* __restrict__ w_mini, const float* __restrict__ w_mid,
    const float* __restrict__ w_midmini, const float* __restrict__ w_final,
    unsigned short* __restrict__ wswz, unsigned short* __restrict__ cfrag,
    unsigned short* __restrict__ x_bf)
{
    const int t = threadIdx.x;
    if (blockIdx.x < 1250) {
        int row = blockIdx.x * 16 + (t >> 4);
        int l16 = t & 15;
        const float4* xr = (const float4*)&x[(size_t)row * CH + l16 * 8];
        float4 a = xr[0], b = xr[1];
        if (x_bf) {
            us8 v;
            v[0] = f2bf(a.x); v[1] = f2bf(a.y); v[2] = f2bf(a.z); v[3] = f2bf(a.w);
            v[4] = f2bf(b.x); v[5] = f2bf(b.y); v[6] = f2bf(b.z); v[7] = f2bf(b.w);
            *(us8*)&x_bf[(size_t)row * CH + l16 * 8] = v;
        }
        double s = (double)a.x + a.y + a.z + a.w + b.x + b.y + b.z + b.w;
        #pragma unroll
        for (int off = 8; off > 0; off >>= 1) s += __shfl_down(s, off, 64);
        if (l16 == 0) rowsum[row] = (float)s;
    } else if (blockIdx.x < 2530) {
        int gid = (blockIdx.x - 1250) * 256 + t;
        if (gid >= NKT * 8 * 512) return;
        int j = gid & 7;
        int l = (gid >> 3) & 63;
        int ntkt = gid >> 9;
        int nt = ntkt & 7;
        int kt = ntkt >> 3;
        int kg = kt * 32 + ((l >> 4) << 3) + j;
        int d  = nt * 16 + (l & 15);
        int k = kg >> 7, c = kg & 127;
        float v = 0.0f;
        if (k < KMINI && d < DH)        v = w_mini[((size_t)k * CH + c) * DH + d];
        else if (k >= KMINI && d >= DH) v = w_mid[((size_t)(k - KMINI) * CH + c) * DH + (d - DH)];
        wswz[gid] = f2bf(v);
    } else {
        // fused tail matrix C, LDS-staged (kills the 64 serial uncoalesced loads)
        __shared__ float wm[4096];       // w_midmini 64x64
        __shared__ float wfs[16][64];    // w_final[jcol][64..127] slice
        __shared__ float wfd[16][32];    // w_final[jcol][kt*32..+31] slice
        int b2 = blockIdx.x - 2530;      // 0..31 -> (kt, nt)
        int kt = b2 >> 3, nt = b2 & 7;
        for (int e = t; e < 4096; e += 256) wm[e] = w_midmini[e];
        for (int e = t; e < 1024; e += 256) {
            int r = e >> 6, dd = e & 63;
            wfs[r][dd] = w_final[(size_t)(nt * 16 + r) * 128 + 64 + dd];
        }
        for (int e = t; e < 512; e += 256) {
            int r = e >> 5, i2 = e & 31;
            int col = kt * 32 + i2;
            wfd[r][i2] = (col < 64) ? w_final[(size_t)(nt * 16 + r) * 128 + col] : 0.f;
        }
        __syncthreads();
        for (int e = t; e < 512; e += 256) {
            int l = e >> 3, j = e & 7;
            int i = kt * 32 + ((l >> 4) << 3) + j;
            int r = l & 15;
            int ec = i & 63;
            float dsum = 0.f;
            #pragma unroll 8
            for (int dd = 0; dd < 64; ++dd)
                dsum += wm[dd * 64 + ec] * wfs[r][dd];
            float cv = dsum + ((i < 64) ? wfd[r][i - kt * 32] : 0.f);
            cfrag[(size_t)(kt * 8 + nt) * 512 + e] = f2bf(cv);
        }
    }
}

// --------- kernel F2: fused gather(bf16, pipelined) + MFMA weight + main GEMM -
__global__ __launch_bounds__(256) void k_fused2(
    const float* __restrict__ q_pts, const float* __restrict__ s_pts,
    const int* __restrict__ inds, const unsigned short* __restrict__ x_bf,
    const float* __restrict__ kp_mini, const float* __restrict__ kp_mid,
    const float* __restrict__ rowsum, const unsigned short* __restrict__ wswz,
    const int* __restrict__ stacklen,
    float* __restrict__ y1, float* __restrict__ y2, float* __restrict__ segsum)
{
    __shared__ __align__(16) char pool[36096];
    unsigned short* Pt = (unsigned short*)pool;
    unsigned short* xg = (unsigned short*)(pool + 26880);
    float* nbv = (float*)pool;
    __shared__ int nidx[512];
    __shared__ float kpts[KTOT][3];
    __shared__ int vcnt[16];
    __shared__ float winv[16];

    const int t = threadIdx.x;
    const int l = t & 63;
    const int w = t >> 6;
    const int c16 = l & 15;
    const int quad = l >> 4;
    const int n0 = blockIdx.x * 16;

    if (t < KTOT * 3) {
        int k = t / 3, j = t % 3;
        kpts[k][j] = (k < KMINI) ? kp_mini[k * 3 + j] : kp_mid[(k - KMINI) * 3 + j];
    }
    if (t < 16) vcnt[t] = 0;
    __syncthreads();

    // phase 0: neighbor vectors + validity counts
    for (int tt = t; tt < 512; tt += 256) {
        int r = tt >> 5, h = tt & 31;
        int n = n0 + r;
        int idx = inds[n * HN + h];
        nidx[tt] = idx;
        float qx = q_pts[n * 3 + 0], qy = q_pts[n * 3 + 1], qz = q_pts[n * 3 + 2];
        nbv[tt * 3 + 0] = s_pts[idx * 3 + 0] - qx;
        nbv[tt * 3 + 1] = s_pts[idx * 3 + 1] - qy;
        nbv[tt * 3 + 2] = s_pts[idx * 3 + 2] - qz;
        if (rowsum[idx] > 0.0f) atomicAdd(&vcnt[r], 1);
    }
    __syncthreads();
    if (t < 16) winv[t] = 1.0f / (float)max(vcnt[t], 1);
    __syncthreads();

    // phase 1: influence A-fragments in registers
    bf16x8 aw0[4], aw1[4];
    const float k0x = kpts[c16][0], k0y = kpts[c16][1], k0z = kpts[c16][2];
    const bool v1 = (c16 < 4);
    const float k1x = v1 ? kpts[16 + c16][0] : 0.f;
    const float k1y = v1 ? kpts[16 + c16][1] : 0.f;
    const float k1z = v1 ? kpts[16 + c16][2] : 0.f;
    #pragma unroll
    for (int s = 0; s < 4; ++s) {
        const int qi = w * 4 + s;
        const float wi = winv[qi];
        const float* nvb = nbv + (qi * 32 + quad * 8) * 3;
        #pragma unroll
        for (int j = 0; j < 8; ++j) {
            float bx = nvb[j * 3 + 0], by = nvb[j * 3 + 1], bz = nvb[j * 3 + 2];
            float dx = bx - k0x, dy = by - k0y, dz = bz - k0z;
            float d = sqrtf(fmaxf(dx * dx + dy * dy + dz * dz, 1e-12f));
            aw0[s][j] = (short)f2bf(fmaxf(1.0f - d * (1.0f / 0.6f), 0.0f) * wi);
            if (v1) {
                dx = bx - k1x; dy = by - k1y; dz = bz - k1z;
                d = sqrtf(fmaxf(dx * dx + dy * dy + dz * dz, 1e-12f));
                aw1[s][j] = (short)f2bf(fmaxf(1.0f - d * (1.0f / 0.6f), 0.0f) * wi);
            } else {
                aw1[s][j] = 0;
            }
        }
    }

    // gather pointers for this thread (rows hA and hB of each of its 4 queries)
    const int hA = l >> 2, c8 = l & 3;
    const int hB = 16 + hA;
    const unsigned short* pA[4];
    const unsigned short* pB[4];
    #pragma unroll
    for (int s = 0; s < 4; ++s) {
        int qi = w * 4 + s;
        pA[s] = x_bf + (size_t)nidx[qi * 32 + hA] * CH + c8 * 8;
        pB[s] = x_bf + (size_t)nidx[qi * 32 + hB] * CH + c8 * 8;
    }
    __syncthreads();   // nbv dead; Pt/xg live

    f32x4 accY1 = (f32x4){0.f, 0.f, 0.f, 0.f};
    f32x4 accY2 = (f32x4){0.f, 0.f, 0.f, 0.f};
    unsigned short* xgw = xg + w * (32 * 36);
    const f32x4 zero4 = (f32x4){0.f, 0.f, 0.f, 0.f};

    // software pipeline: prefetch next (ktc,s) gather while computing current
    us8 pfA = *(const us8*)(pA[0]);
    us8 pfB = *(const us8*)(pB[0]);

    for (int ktc = 0; ktc < 4; ++ktc) {
        #pragma unroll
        for (int s = 0; s < 4; ++s) {
            const int qi = w * 4 + s;
            // store current prefetched rows into xgw
            {
                us4 va = (us4){(unsigned short)pfA[0], (unsigned short)pfA[1],
                               (unsigned short)pfA[2], (unsigned short)pfA[3]};
                us4 vb = (us4){(unsigned short)pfA[4], (unsigned short)pfA[5],
                               (unsigned short)pfA[6], (unsigned short)pfA[7]};
                *(us4*)&xgw[hA * 36 + c8 * 8]     = va;
                *(us4*)&xgw[hA * 36 + c8 * 8 + 4] = vb;
                us4 vc = (us4){(unsigned short)pfB[0], (unsigned short)pfB[1],
                               (unsigned short)pfB[2], (unsigned short)pfB[3]};
                us4 vd = (us4){(unsigned short)pfB[4], (unsigned short)pfB[5],
                               (unsigned short)pfB[6], (unsigned short)pfB[7]};
                *(us4*)&xgw[hB * 36 + c8 * 8]     = vc;
                *(us4*)&xgw[hB * 36 + c8 * 8 + 4] = vd;
            }
            // issue next gather immediately (overlaps with frag reads + MFMAs)
            const int nit = ktc * 4 + s + 1;
            if (nit < 16) {
                const int nktc = nit >> 2, ns = nit & 3;
                pfA = *(const us8*)(pA[ns] + nktc * 32);
                pfB = *(const us8*)(pB[ns] + nktc * 32);
            }
            asm volatile("s_waitcnt lgkmcnt(0)" ::: "memory");
            #pragma unroll
            for (int cf = 0; cf < 2; ++cf) {
                bf16x8 bb;
                #pragma unroll
                for (int j = 0; j < 8; ++j)
                    bb[j] = (short)xgw[(quad * 8 + j) * 36 + cf * 16 + c16];
                f32x4 d0 = __builtin_amdgcn_mfma_f32_16x16x32_bf16(aw0[s], bb, zero4, 0, 0, 0);
                f32x4 d1 = __builtin_amdgcn_mfma_f32_16x16x32_bf16(aw1[s], bb, zero4, 0, 0, 0);
                unsigned short* pq = Pt + qi * PQ + cf * 16 + c16;
                #pragma unroll
                for (int reg = 0; reg < 4; ++reg)
                    pq[(quad * 4 + reg) * PK] = f2bf(d0[reg]);
                if (quad == 0) {
                    #pragma unroll
                    for (int reg = 0; reg < 4; ++reg)
                        pq[(16 + reg) * PK] = f2bf(d1[reg]);
                }
            }
        }
        __syncthreads();   // Pt complete for this c-quarter

        #pragma unroll
        for (int k = 0; k < KTOT; ++k) {
            int ktg = k * 4 + ktc;
            bf16x8 a = *(const bf16x8*)&Pt[c16 * PQ + k * PK + quad * 8];
            int nt = (k < KMINI) ? w : 4 + w;
            bf16x8 b = *(const bf16x8*)&wswz[((size_t)(ktg * 8 + nt) << 9) + l * 8];
            if (k < KMINI) accY1 = __builtin_amdgcn_mfma_f32_16x16x32_bf16(a, b, accY1, 0, 0, 0);
            else           accY2 = __builtin_amdgcn_mfma_f32_16x16x32_bf16(a, b, accY2, 0, 0, 0);
        }
        __syncthreads();
    }

    // epilogue: store y + fused segment stats
    const int len0 = stacklen[0];
    const bool all0 = (n0 + 15 < len0);
    const bool all1 = (n0 >= len0);
    const int ch = w * 16 + c16;
    #pragma unroll
    for (int half = 0; half < 2; ++half) {
        f32x4 acc = half ? accY2 : accY1;
        float* yb = half ? y2 : y1;
        const int sbase = half ? 256 : 0;
        float s0 = 0.f, q0 = 0.f, s1 = 0.f, q1 = 0.f;
        #pragma unroll
        for (int reg = 0; reg < 4; ++reg) {
            int row = n0 + quad * 4 + reg;
            float v = acc[reg];
            yb[(size_t)row * DH + ch] = v;
            if (row < len0) { s0 += v; q0 += v * v; }
            else            { s1 += v; q1 += v * v; }
        }
        s0 += __shfl_xor(s0, 16); s0 += __shfl_xor(s0, 32);
        q0 += __shfl_xor(q0, 16); q0 += __shfl_xor(q0, 32);
        s1 += __shfl_xor(s1, 16); s1 += __shfl_xor(s1, 32);
        q1 += __shfl_xor(q1, 16); q1 += __shfl_xor(q1, 32);
        if (quad == 0) {
            if (!all1) {
                atomicAdd(&segsum[sbase + 0 * 64 + ch], s0);
                atomicAdd(&segsum[sbase + 1 * 64 + ch], q0);
            }
            if (!all0) {
                atomicAdd(&segsum[sbase + 2 * 64 + ch], s1);
                atomicAdd(&segsum[sbase + 3 * 64 + ch], q1);
            }
        }
    }
}

// -------- kernel T: fused tail GEMM (norm folded into A) + BN partials --------
__global__ __launch_bounds__(128) void k_tailmm(
    const float* __restrict__ y1, const float* __restrict__ y2,
    const float* __restrict__ segsum, const int* __restrict__ stacklen,
    const unsigned short* __restrict__ cfrag,
    float* __restrict__ outpre, float* __restrict__ bnsum, float* __restrict__ bnsq)
{
    __shared__ __align__(16) unsigned short alds[32 * 136];
    __shared__ float sstat[4][2][64];
    const int t = threadIdx.x;
    const int mb = blockIdx.x * 32;
    const int len0 = stacklen[0];

    for (int tt = t; tt < 256; tt += 128) {
        int combo = tt >> 6, ch = tt & 63;
        float cnt = (float)max((combo & 1) ? (NQ - len0) : len0, 1);
        float S = segsum[(combo * 2 + 0) * 64 + ch];
        float Q = segsum[(combo * 2 + 1) * 64 + ch];
        float mean = S / cnt;
        float var = Q / cnt - mean * mean;
        sstat[combo][0][ch] = mean;
        sstat[combo][1][ch] = rsqrtf(fmaxf(var, 0.f) + EPSN);
    }
    __syncthreads();

    for (int tt = t; tt < 32 * 32; tt += 128) {
        int r = tt >> 5, c4 = tt & 31;
        int n = mb + r;
        us4 v4 = (us4){0, 0, 0, 0};
        if (n < NQ) {
            int s = (n >= len0) ? 1 : 0;
            int c = c4 * 4;
            if (c < 64) {
                float4 yv = *(const float4*)&y1[(size_t)n * DH + c];
                v4[0] = f2bf((yv.x - sstat[s][0][c + 0]) * sstat[s][1][c + 0]);
                v4[1] = f2bf((yv.y - sstat[s][0][c + 1]) * sstat[s][1][c + 1]);
                v4[2] = f2bf((yv.z - sstat[s][0][c + 2]) * sstat[s][1][c + 2]);
                v4[3] = f2bf((yv.w - sstat[s][0][c + 3]) * sstat[s][1][c + 3]);
            } else {
                int c2 = c - 64;
                float4 yv = *(const float4*)&y2[(size_t)n * DH + c2];
                v4[0] = f2bf((yv.x - sstat[2 + s][0][c2 + 0]) * sstat[2 + s][1][c2 + 0]);
                v4[1] = f2bf((yv.y - sstat[2 + s][0][c2 + 1]) * sstat[2 + s][1][c2 + 1]);
                v4[2] = f2bf((yv.z - sstat[2 + s][0][c2 + 2]) * sstat[2 + s][1][c2 + 2]);
                v4[3] = f2bf((yv.w - sstat[2 + s][0][c2 + 3]) * sstat[2 + s][1][c2 + 3]);
            }
        }
        *(us4*)(alds + r * 136 + c4 * 4) = v4;
    }
    __syncthreads();

    const int l = t & 63, w = t >> 6;
    f32x4 acc[8];
    #pragma unroll
    for (int q = 0; q < 8; ++q) acc[q] = (f32x4){0.f, 0.f, 0.f, 0.f};

    const unsigned short* ap = alds + (w * 16 + (l & 15)) * 136 + ((l >> 4) << 3);
    const unsigned short* bp = cfrag + l * 8;
    #pragma unroll
    for (int kt = 0; kt < 4; ++kt) {
        bf16x8 a = *(const bf16x8*)(ap + kt * 32);
        #pragma unroll
        for (int nt = 0; nt < 8; ++nt) {
            bf16x8 b = *(const bf16x8*)(bp + (size_t)((kt * 8 + nt) << 9));
            acc[nt] = __builtin_amdgcn_mfma_f32_16x16x32_bf16(a, b, acc[nt], 0, 0, 0);
        }
    }

    const int quad = l >> 4, c16 = l & 15;
    #pragma unroll
    for (int nt = 0; nt < 8; ++nt) {
        float s = 0.f, q = 0.f;
        #pragma unroll
        for (int reg = 0; reg < 4; ++reg) {
            int row = mb + w * 16 + quad * 4 + reg;
            float v = acc[nt][reg];
            if (row < NQ) outpre[(size_t)row * CH + nt * 16 + c16] = v;
            else v = 0.f;
            s += v; q += v * v;
        }
        s += __shfl_xor(s, 16); s += __shfl_xor(s, 32);
        q += __shfl_xor(q, 16); q += __shfl_xor(q, 32);
        if (quad == 0) {
            atomicAdd(&bnsum[nt * 16 + c16], s);
            atomicAdd(&bnsq[nt * 16 + c16], q);
        }
    }
}

// ---------------- FALLBACK kernels (ws too small) -----------------------------
__global__ __launch_bounds__(256) void k_kpconv(
    const float* __restrict__ q_pts, const float* __restrict__ s_pts,
    const int* __restrict__ inds, const float* __restrict__ x,
    const float* __restrict__ kp_mini, const float* __restrict__ kp_mid,
    const float* __restrict__ w_mini, const float* __restrict__ w_mid,
    const float* __restrict__ rowsum,
    float* __restrict__ y1, float* __restrict__ y2)
{
    __shared__ __align__(16) float kpts[KTOT][3];
    __shared__ __align__(16) float nb[128][3];
    __shared__ int   nidx[128];
    __shared__ int   vcnt[4];
    __shared__ float winv[4];
    __shared__ __align__(16) float wts[4][HN][KTOT];
    __shared__ __align__(16) float wt[KTOT][CH][4];
    __shared__ __align__(16) float part[128][4];

    const int t = threadIdx.x;
    const int n0 = blockIdx.x * 4;

    if (t < KTOT * 3) {
        int k = t / 3, j = t % 3;
        kpts[k][j] = (k < KMINI) ? kp_mini[k * 3 + j] : kp_mid[(k - KMINI) * 3 + j];
    }
    if (t < 4) vcnt[t] = 0;
    __syncthreads();

    if (t < 128) {
        int r = t >> 5, h = t & 31;
        int n = n0 + r;
        int idx = inds[n * HN + h];
        nidx[t] = idx;
        float qx = q_pts[n * 3 + 0], qy = q_pts[n * 3 + 1], qz = q_pts[n * 3 + 2];
        nb[t][0] = s_pts[idx * 3 + 0] - qx;
        nb[t][1] = s_pts[idx * 3 + 1] - qy;
        nb[t][2] = s_pts[idx * 3 + 2] - qz;
        if (rowsum[idx] > 0.0f) atomicAdd(&vcnt[r], 1);
    }
    __syncthreads();
    if (t < 4) winv[t] = 1.0f / (float)max(vcnt[t], 1);
    __syncthreads();

    for (int tt = t; tt < 4 * HN * KTOT; tt += 256) {
        int r = tt / (HN * KTOT);
        int rem = tt % (HN * KTOT);
        int h = rem / KTOT, k = rem % KTOT;
        float dx = nb[r * HN + h][0] - kpts[k][0];
        float dy = nb[r * HN + h][1] - kpts[k][1];
        float dz = nb[r * HN + h][2] - kpts[k][2];
        float sq = dx * dx + dy * dy + dz * dz;
        float dist = sqrtf(fmaxf(sq, 1e-12f));
        float w = fmaxf(1.0f - dist * (1.0f / 0.6f), 0.0f);
        wts[r][h][k] = w * winv[r];
    }
    __syncthreads();

    {
        const int g = t >> 7;
        const int c = t & 127;
        for (int rr = 0; rr < 2; ++rr) {
            const int r = g + rr * 2;
            float acc[KTOT];
            #pragma unroll
            for (int k = 0; k < KTOT; ++k) acc[k] = 0.0f;
            for (int h = 0; h < HN; ++h) {
                int idx = nidx[r * HN + h];
                float xv = x[(size_t)idx * CH + c];
                const float4* wp = (const float4*)&wts[r][h][0];
                float4 wa = wp[0], wb = wp[1], wc = wp[2], wd = wp[3], we = wp[4];
                acc[0]  += wa.x * xv; acc[1]  += wa.y * xv; acc[2]  += wa.z * xv; acc[3]  += wa.w * xv;
                acc[4]  += wb.x * xv; acc[5]  += wb.y * xv; acc[6]  += wb.z * xv; acc[7]  += wb.w * xv;
                acc[8]  += wc.x * xv; acc[9]  += wc.y * xv; acc[10] += wc.z * xv; acc[11] += wc.w * xv;
                acc[12] += wd.x * xv; acc[13] += wd.y * xv; acc[14] += wd.z * xv; acc[15] += wd.w * xv;
                acc[16] += we.x * xv; acc[17] += we.y * xv; acc[18] += we.z * xv; acc[19] += we.w * xv;
            }
            #pragma unroll
            for (int k = 0; k < KTOT; ++k) wt[k][c][r] = acc[k];
        }
    }
    __syncthreads();

    {
        const int d = t & 127;
        const int half = t >> 7;
        const int c0 = half * 64;
        float o0 = 0.f, o1 = 0.f, o2 = 0.f, o3 = 0.f;
        if (d < DH) {
            for (int k = 0; k < KMINI; ++k) {
                const float* wp = &w_mini[((size_t)k * CH + c0) * DH + d];
                for (int c = c0; c < c0 + 64; ++c) {
                    float wv = *wp; wp += DH;
                    const float4 wtv = *(const float4*)&wt[k][c][0];
                    o0 += wv * wtv.x; o1 += wv * wtv.y; o2 += wv * wtv.z; o3 += wv * wtv.w;
                }
            }
        } else {
            const int dd = d - DH;
            for (int k = KMINI; k < KTOT; ++k) {
                const float* wp = &w_mid[((size_t)(k - KMINI) * CH + c0) * DH + dd];
                for (int c = c0; c < c0 + 64; ++c) {
                    float wv = *wp; wp += DH;
                    const float4 wtv = *(const float4*)&wt[k][c][0];
                    o0 += wv * wtv.x; o1 += wv * wtv.y; o2 += wv * wtv.z; o3 += wv * wtv.w;
                }
            }
        }
        if (half == 1) { part[d][0] = o0; part[d][1] = o1; part[d][2] = o2; part[d][3] = o3; }
        __syncthreads();
        if (half == 0) {
            o0 += part[d][0]; o1 += part[d][1]; o2 += part[d][2]; o3 += part[d][3];
            if (d < DH) {
                y1[(size_t)(n0 + 0) * DH + d] = o0;
                y1[(size_t)(n0 + 1) * DH + d] = o1;
                y1[(size_t)(n0 + 2) * DH + d] = o2;
                y1[(size_t)(n0 + 3) * DH + d] = o3;
            } else {
                const int dd = d - DH;
                y2[(size_t)(n0 + 0) * DH + dd] = o0;
                y2[(size_t)(n0 + 1) * DH + dd] = o1;
                y2[(size_t)(n0 + 2) * DH + dd] = o2;
                y2[(size_t)(n0 + 3) * DH + dd] = o3;
            }
        }
    }
}

__global__ __launch_bounds__(256) void k_segpart(
    const float* __restrict__ y1, const float* __restrict__ y2,
    const int* __restrict__ stacklen, float* __restrict__ segsum)
{
    const int t = threadIdx.x;
    const int ch = t & 63, grp = t >> 6;
    const int len0 = stacklen[0];
    float a0 = 0.f, a1 = 0.f, a2 = 0.f, a3 = 0.f;
    float b0 = 0.f, b1 = 0.f, b2 = 0.f, b3 = 0.f;
    for (int r = blockIdx.x * 4 + grp; r < NQ; r += 256 * 4) {
        float v1 = y1[(size_t)r * DH + ch];
        float v2 = y2[(size_t)r * DH + ch];
        bool in1 = (r >= len0);
        float m0 = in1 ? 0.f : 1.f, m1 = 1.f - m0;
        a0 += m0 * v1; a1 += m0 * v1 * v1; a2 += m1 * v1; a3 += m1 * v1 * v1;
        b0 += m0 * v2; b1 += m0 * v2 * v2; b2 += m1 * v2; b3 += m1 * v2 * v2;
    }
    __shared__ float red[4][8][64];
    red[grp][0][ch] = a0; red[grp][1][ch] = a1; red[grp][2][ch] = a2; red[grp][3][ch] = a3;
    red[grp][4][ch] = b0; red[grp][5][ch] = b1; red[grp][6][ch] = b2; red[grp][7][ch] = b3;
    __syncthreads();
    for (int tt = t; tt < 512; tt += 256) {
        int j = tt >> 6, c = tt & 63;
        float s = red[0][j][c] + red[1][j][c] + red[2][j][c] + red[3][j][c];
        atomicAdd(&segsum[j * 64 + c], s);
    }
}

__global__ __launch_bounds__(256) void k_tail(
    const float* __restrict__ y1, const float* __restrict__ y2,
    const float* __restrict__ segsum, const int* __restrict__ stacklen,
    const float* __restrict__ w_midmini, const float* __restrict__ w_final,
    float* __restrict__ outpre, float* __restrict__ bnsum, float* __restrict__ bnsq)
{
    __shared__ __align__(16) float sstat[4][2][64];
    __shared__ __align__(16) float sbuf[8][64];
    __shared__ __align__(16) float xc[8][128];
    __shared__ float lsum[2][128], lsq[2][128];
    const int n0 = blockIdx.x * 8;
    const int t = threadIdx.x;
    const int len0 = stacklen[0];

    {
        int combo = t >> 6, ch = t & 63;
        float cnt = (float)max((combo & 1) ? (NQ - len0) : len0, 1);
        float S = segsum[(combo * 2 + 0) * 64 + ch];
        float Q = segsum[(combo * 2 + 1) * 64 + ch];
        float mean = S / cnt;
        float var = Q / cnt - mean * mean;
        sstat[combo][0][ch] = mean;
        sstat[combo][1][ch] = rsqrtf(fmaxf(var, 0.f) + EPSN);
    }
    __syncthreads();

    for (int tt = t; tt < 8 * 64; tt += 256) {
        int r = tt >> 6, d = tt & 63;
        int n = n0 + r;
        int s = (n >= len0) ? 1 : 0;
        float x1n = (y1[(size_t)n * DH + d] - sstat[s][0][d]) * sstat[s][1][d];
        float x2n = (y2[(size_t)n * DH + d] - sstat[2 + s][0][d]) * sstat[2 + s][1][d];
        xc[r][d] = x1n;
        sbuf[r][d] = x1n + x2n;
    }
    __syncthreads();

    for (int tt = t; tt < 8 * 64; tt += 256) {
        int r = tt >> 6, d = tt & 63;
        float a = 0.f;
        const float4* wmr = (const float4*)&w_midmini[(size_t)d * 64];
        const float4* sv = (const float4*)&sbuf[r][0];
        #pragma unroll
        for (int e4 = 0; e4 < 16; ++e4) {
            float4 w4 = wmr[e4], s4 = sv[e4];
            a += w4.x * s4.x + w4.y * s4.y + w4.z * s4.z + w4.w * s4.w;
        }
        xc[r][64 + d] = a;
    }
    __syncthreads();

    {
        const int j = t & 127;
        const int g = t >> 7;
        float o0 = 0.f, o1 = 0.f, o2 = 0.f, o3 = 0.f;
        const float4* wfr = (const float4*)&w_final[(size_t)j * 128];
        #pragma unroll 8
        for (int i4 = 0; i4 < 32; ++i4) {
            float4 wf = wfr[i4];
            float4 a0 = *(const float4*)&xc[g + 0][i4 * 4];
            float4 a1 = *(const float4*)&xc[g + 2][i4 * 4];
            float4 a2 = *(const float4*)&xc[g + 4][i4 * 4];
            float4 a3 = *(const float4*)&xc[g + 6][i4 * 4];
            o0 += wf.x * a0.x + wf.y * a0.y + wf.z * a0.z + wf.w * a0.w;
            o1 += wf.x * a1.x + wf.y * a1.y + wf.z * a1.z + wf.w * a1.w;
            o2 += wf.x * a2.x + wf.y * a2.y + wf.z * a2.z + wf.w * a2.w;
            o3 += wf.x * a3.x + wf.y * a3.y + wf.z * a3.z + wf.w * a3.w;
        }
        outpre[(size_t)(n0 + g + 0) * CH + j] = o0;
        outpre[(size_t)(n0 + g + 2) * CH + j] = o1;
        outpre[(size_t)(n0 + g + 4) * CH + j] = o2;
        outpre[(size_t)(n0 + g + 6) * CH + j] = o3;
        lsum[g][j] = o0 + o1 + o2 + o3;
        lsq[g][j]  = o0 * o0 + o1 * o1 + o2 * o2 + o3 * o3;
        __syncthreads();
        if (g == 0) {
            atomicAdd(&bnsum[j], lsum[0][j] + lsum[1][j]);
            atomicAdd(&bnsq[j],  lsq[0][j] + lsq[1][j]);
        }
    }
}

// ---------------- kernel 5: BN apply + relu ----------------------------------
__global__ __launch_bounds__(256) void k_bnapply(const float* __restrict__ outpre,
    const float* __restrict__ bnsum, const float* __restrict__ bnsq,
    const float* __restrict__ gamma, const float* __restrict__ beta,
    float* __restrict__ out)
{
    int e4 = blockIdx.x * 256 + threadIdx.x;
    if (e4 >= NQ * CH / 4) return;
    int j0 = (e4 * 4) & 127;
    float4 v = ((const float4*)outpre)[e4];
    float vv[4] = {v.x, v.y, v.z, v.w};
    float res[4];
    #pragma unroll
    for (int i = 0; i < 4; ++i) {
        int j = j0 + i;
        float mean = bnsum[j] * (1.0f / NQ);
        float var = bnsq[j] * (1.0f / NQ) - mean * mean;
        float rstd = rsqrtf(fmaxf(var, 0.f) + EPSN);
        float r = (vv[i] - mean) * rstd * gamma[j] + beta[j];
        res[i] = fmaxf(r, 0.f);
    }
    ((float4*)out)[e4] = make_float4(res[0], res[1], res[2], res[3]);
}

extern "C" void kernel_launch(void* const* d_in, const int* in_sizes, int n_in,
                              void* d_out, int out_size, void* d_ws, size_t ws_size,
                              hipStream_t stream) {
    const float* q_pts     = (const float*)d_in[0];
    const float* s_pts     = (const float*)d_in[1];
    const int*   inds      = (const int*)d_in[2];
    const float* x         = (const float*)d_in[3];
    const int*   stacklen  = (const int*)d_in[4];
    const float* kp_mini   = (const float*)d_in[5];
    const float* w_mini    = (const float*)d_in[6];
    const float* kp_mid    = (const float*)d_in[7];
    const float* w_mid     = (const float*)d_in[8];
    const float* w_midmini = (const float*)d_in[9];
    const float* w_final   = (const float*)d_in[10];
    const float* gamma     = (const float*)d_in[11];
    const float* beta      = (const float*)d_in[12];

    float* ws      = (float*)d_ws;
    float* rowsum  = ws + OFF_ROWSUM;
    float* y1      = ws + OFF_Y1;
    float* y2      = ws + OFF_Y2;
    float* segsum  = ws + OFF_SEGSUM;
    float* bnsum   = ws + OFF_BNSUM;
    float* bnsq    = ws + OFF_BNSQ;
    float* outpre  = ws + OFF_OUTPRE;
    unsigned short* wswz  = (unsigned short*)(ws + OFF_WSWZ);
    unsigned short* cfrag = (unsigned short*)(ws + OFF_CFRAG);
    unsigned short* x_bf  = (unsigned short*)(ws + OFF_XBF);

    hipMemsetAsync(segsum, 0, 768 * sizeof(float), stream);

    if (ws_size >= (size_t)TOT_FLOATS * sizeof(float)) {
        k_prep<<<1250 + 1280 + 32, 256, 0, stream>>>(x, rowsum, w_mini, w_mid,
                                                     w_midmini, w_final, wswz, cfrag, x_bf);
        k_fused2<<<NQ / 16, 256, 0, stream>>>(q_pts, s_pts, inds, x_bf, kp_mini, kp_mid,
                                              rowsum, wswz, stacklen, y1, y2, segsum);
        k_tailmm<<<(NQ + 31) / 32, 128, 0, stream>>>(y1, y2, segsum, stacklen, cfrag,
                                                     outpre, bnsum, bnsq);
    } else {
        k_prep<<<1250, 256, 0, stream>>>(x, rowsum, w_mini, w_mid,
                                         w_midmini, w_final, wswz, cfrag, (unsigned short*)0);
        k_kpconv<<<NQ / 4, 256, 0, stream>>>(q_pts, s_pts, inds, x, kp_mini, kp_mid,
                                             w_mini, w_mid, rowsum, y1, y2);
        k_segpart<<<256, 256, 0, stream>>>(y1, y2, stacklen, segsum);
        k_tail<<<NQ / 8, 256, 0, stream>>>(y1, y2, segsum, stacklen, w_midmini, w_final,
                                           outpre, bnsum, bnsq);
    }

    k_bnapply<<<(NQ * CH / 4 + 255) / 256, 256, 0, stream>>>(outpre, bnsum, bnsq,
                                                             gamma, beta, (float*)d_out);
}

// Round 14
// 228.987 us; speedup vs baseline: 1.0835x; 1.0835x over previous
//
#include <hip/hip_runtime.h>
#include <math.h>

#define NQ 20000
#define MS 20000
#define HN 32
#define CH 128
#define DH 64
#define KTOT 20
#define KMINI 7
#define EPSN 1e-5f
#define NKT 80
#define KT_Y1 28

// workspace layout (float units)
#define OFF_ROWSUM 0
#define OFF_Y1     20480
#define OFF_Y2     (OFF_Y1 + NQ*DH)
#define OFF_SEGSUM (OFF_Y2 + NQ*DH)           // 512, zeroed
#define OFF_BNSUM  (OFF_SEGSUM + 512)         // 128, zeroed
#define OFF_BNSQ   (OFF_BNSUM + 128)          // 128, zeroed
#define OFF_OUTPRE (OFF_BNSQ + 128)           // NQ*CH
#define OFF_WSWZ   (OFF_OUTPRE + NQ*CH)       // 327680 ushort
#define OFF_CFRAG  (OFF_WSWZ + 163840)        // 16384 ushort
#define OFF_XBF    (OFF_CFRAG + 8192)         // NQ*CH ushort
#define TOT_FLOATS (OFF_XBF + NQ*CH/2)

// Pt LDS pitches (elements)
#define PK 40                 // k-row stride
#define PQ 840                // query stride (21*40)

typedef __attribute__((ext_vector_type(8))) short bf16x8;
typedef __attribute__((ext_vector_type(4))) float f32x4;
typedef __attribute__((ext_vector_type(4))) unsigned short us4;
typedef __attribute__((ext_vector_type(8))) unsigned short us8;

static __device__ inline unsigned short f2bf(float f) {
    unsigned int u = __float_as_uint(f);
    unsigned int r = (u + 0x7fffu + ((u >> 16) & 1u)) >> 16;
    return (unsigned short)r;
}

// --- kernel P: rowsum+x_bf (<1250) | weight swizzle (<2530) | C frags (rest) --
__global__ __launch_bounds__(256) void k_prep(
    const float* __restrict__ x, float* __restrict__ rowsum,
    const float* __restrict__ w_mini, const float* __restrict__ w_mid,
    const float* __restrict__ w_midmini, const float* __restrict__ w_final,
    unsigned short* __restrict__ wswz, unsigned short* __restrict__ cfrag,
    unsigned short* __restrict__ x_bf)
{
    const int t = threadIdx.x;
    if (blockIdx.x < 1250) {
        int row = blockIdx.x * 16 + (t >> 4);
        int l16 = t & 15;
        const float4* xr = (const float4*)&x[(size_t)row * CH + l16 * 8];
        float4 a = xr[0], b = xr[1];
        if (x_bf) {
            us8 v;
            v[0] = f2bf(a.x); v[1] = f2bf(a.y); v[2] = f2bf(a.z); v[3] = f2bf(a.w);
            v[4] = f2bf(b.x); v[5] = f2bf(b.y); v[6] = f2bf(b.z); v[7] = f2bf(b.w);
            *(us8*)&x_bf[(size_t)row * CH + l16 * 8] = v;
        }
        double s = (double)a.x + a.y + a.z + a.w + b.x + b.y + b.z + b.w;
        #pragma unroll
        for (int off = 8; off > 0; off >>= 1) s += __shfl_down(s, off, 64);
        if (l16 == 0) rowsum[row] = (float)s;
    } else if (blockIdx.x < 2530) {
        int gid = (blockIdx.x - 1250) * 256 + t;
        if (gid >= NKT * 8 * 512) return;
        int j = gid & 7;
        int l = (gid >> 3) & 63;
        int ntkt = gid >> 9;
        int nt = ntkt & 7;
        int kt = ntkt >> 3;
        int kg = kt * 32 + ((l >> 4) << 3) + j;
        int d  = nt * 16 + (l & 15);
        int k = kg >> 7, c = kg & 127;
        float v = 0.0f;
        if (k < KMINI && d < DH)        v = w_mini[((size_t)k * CH + c) * DH + d];
        else if (k >= KMINI && d >= DH) v = w_mid[((size_t)(k - KMINI) * CH + c) * DH + (d - DH)];
        wswz[gid] = f2bf(v);
    } else {
        // fused tail matrix C, LDS-staged
        __shared__ float wm[4096];       // w_midmini 64x64
        __shared__ float wfs[16][64];    // w_final[jcol][64..127] slice
        __shared__ float wfd[16][32];    // w_final[jcol][kt*32..+31] slice
        int b2 = blockIdx.x - 2530;      // 0..31 -> (kt, nt)
        int kt = b2 >> 3, nt = b2 & 7;
        for (int e = t; e < 4096; e += 256) wm[e] = w_midmini[e];
        for (int e = t; e < 1024; e += 256) {
            int r = e >> 6, dd = e & 63;
            wfs[r][dd] = w_final[(size_t)(nt * 16 + r) * 128 + 64 + dd];
        }
        for (int e = t; e < 512; e += 256) {
            int r = e >> 5, i2 = e & 31;
            int col = kt * 32 + i2;
            wfd[r][i2] = (col < 64) ? w_final[(size_t)(nt * 16 + r) * 128 + col] : 0.f;
        }
        __syncthreads();
        for (int e = t; e < 512; e += 256) {
            int l = e >> 3, j = e & 7;
            int i = kt * 32 + ((l >> 4) << 3) + j;
            int r = l & 15;
            int ec = i & 63;
            float dsum = 0.f;
            #pragma unroll 8
            for (int dd = 0; dd < 64; ++dd)
                dsum += wm[dd * 64 + ec] * wfs[r][dd];
            float cv = dsum + ((i < 64) ? wfd[r][i - kt * 32] : 0.f);
            cfrag[(size_t)(kt * 8 + nt) * 512 + e] = f2bf(cv);
        }
    }
}

// --------- kernel F2: fused gather(bf16) + MFMA weighting + MFMA main GEMM ----
// 1250 blocks x 256 thr; block = 16 queries. P lives only in LDS (c-quartered).
__global__ __launch_bounds__(256) void k_fused2(
    const float* __restrict__ q_pts, const float* __restrict__ s_pts,
    const int* __restrict__ inds, const unsigned short* __restrict__ x_bf,
    const float* __restrict__ kp_mini, const float* __restrict__ kp_mid,
    const float* __restrict__ rowsum, const unsigned short* __restrict__ wswz,
    const int* __restrict__ stacklen,
    float* __restrict__ y1, float* __restrict__ y2, float* __restrict__ segsum)
{
    __shared__ __align__(16) char pool[36096];
    unsigned short* Pt = (unsigned short*)pool;
    unsigned short* xg = (unsigned short*)(pool + 26880);
    float* nbv = (float*)pool;
    __shared__ int nidx[512];
    __shared__ float kpts[KTOT][3];
    __shared__ int vcnt[16];
    __shared__ float winv[16];

    const int t = threadIdx.x;
    const int l = t & 63;
    const int w = t >> 6;
    const int c16 = l & 15;
    const int quad = l >> 4;
    const int n0 = blockIdx.x * 16;

    if (t < KTOT * 3) {
        int k = t / 3, j = t % 3;
        kpts[k][j] = (k < KMINI) ? kp_mini[k * 3 + j] : kp_mid[(k - KMINI) * 3 + j];
    }
    if (t < 16) vcnt[t] = 0;
    __syncthreads();

    // phase 0: neighbor vectors + validity counts
    for (int tt = t; tt < 512; tt += 256) {
        int r = tt >> 5, h = tt & 31;
        int n = n0 + r;
        int idx = inds[n * HN + h];
        nidx[tt] = idx;
        float qx = q_pts[n * 3 + 0], qy = q_pts[n * 3 + 1], qz = q_pts[n * 3 + 2];
        nbv[tt * 3 + 0] = s_pts[idx * 3 + 0] - qx;
        nbv[tt * 3 + 1] = s_pts[idx * 3 + 1] - qy;
        nbv[tt * 3 + 2] = s_pts[idx * 3 + 2] - qz;
        if (rowsum[idx] > 0.0f) atomicAdd(&vcnt[r], 1);
    }
    __syncthreads();
    if (t < 16) winv[t] = 1.0f / (float)max(vcnt[t], 1);
    __syncthreads();

    // phase 1: influence A-fragments in registers
    bf16x8 aw0[4], aw1[4];
    const float k0x = kpts[c16][0], k0y = kpts[c16][1], k0z = kpts[c16][2];
    const bool v1 = (c16 < 4);
    const float k1x = v1 ? kpts[16 + c16][0] : 0.f;
    const float k1y = v1 ? kpts[16 + c16][1] : 0.f;
    const float k1z = v1 ? kpts[16 + c16][2] : 0.f;
    #pragma unroll
    for (int s = 0; s < 4; ++s) {
        const int qi = w * 4 + s;
        const float wi = winv[qi];
        const float* nvb = nbv + (qi * 32 + quad * 8) * 3;
        #pragma unroll
        for (int j = 0; j < 8; ++j) {
            float bx = nvb[j * 3 + 0], by = nvb[j * 3 + 1], bz = nvb[j * 3 + 2];
            float dx = bx - k0x, dy = by - k0y, dz = bz - k0z;
            float d = sqrtf(fmaxf(dx * dx + dy * dy + dz * dz, 1e-12f));
            aw0[s][j] = (short)f2bf(fmaxf(1.0f - d * (1.0f / 0.6f), 0.0f) * wi);
            if (v1) {
                dx = bx - k1x; dy = by - k1y; dz = bz - k1z;
                d = sqrtf(fmaxf(dx * dx + dy * dy + dz * dz, 1e-12f));
                aw1[s][j] = (short)f2bf(fmaxf(1.0f - d * (1.0f / 0.6f), 0.0f) * wi);
            } else {
                aw1[s][j] = 0;
            }
        }
    }
    __syncthreads();   // nbv dead; Pt/xg live

    f32x4 accY1 = (f32x4){0.f, 0.f, 0.f, 0.f};
    f32x4 accY2 = (f32x4){0.f, 0.f, 0.f, 0.f};
    unsigned short* xgw = xg + w * (32 * 36);
    const f32x4 zero4 = (f32x4){0.f, 0.f, 0.f, 0.f};

    for (int ktc = 0; ktc < 4; ++ktc) {
        #pragma unroll
        for (int s = 0; s < 4; ++s) {
            const int qi = w * 4 + s;
            // gather this c-quarter (bf16): 2 independent 16B loads, one wait
            #pragma unroll
            for (int i = 0; i < 2; ++i) {
                int gid = i * 64 + l;          // 0..127
                int h = gid >> 2, c8 = gid & 3;
                int idx = nidx[qi * 32 + h];
                us8 v = *(const us8*)&x_bf[(size_t)idx * CH + ktc * 32 + c8 * 8];
                us4 va = (us4){(unsigned short)v[0], (unsigned short)v[1],
                               (unsigned short)v[2], (unsigned short)v[3]};
                us4 vb = (us4){(unsigned short)v[4], (unsigned short)v[5],
                               (unsigned short)v[6], (unsigned short)v[7]};
                *(us4*)&xgw[h * 36 + c8 * 8]     = va;
                *(us4*)&xgw[h * 36 + c8 * 8 + 4] = vb;
            }
            asm volatile("s_waitcnt lgkmcnt(0)" ::: "memory");
            #pragma unroll
            for (int cf = 0; cf < 2; ++cf) {
                bf16x8 bb;
                #pragma unroll
                for (int j = 0; j < 8; ++j)
                    bb[j] = (short)xgw[(quad * 8 + j) * 36 + cf * 16 + c16];
                f32x4 d0 = __builtin_amdgcn_mfma_f32_16x16x32_bf16(aw0[s], bb, zero4, 0, 0, 0);
                f32x4 d1 = __builtin_amdgcn_mfma_f32_16x16x32_bf16(aw1[s], bb, zero4, 0, 0, 0);
                unsigned short* pq = Pt + qi * PQ + cf * 16 + c16;
                #pragma unroll
                for (int reg = 0; reg < 4; ++reg)
                    pq[(quad * 4 + reg) * PK] = f2bf(d0[reg]);
                if (quad == 0) {
                    #pragma unroll
                    for (int reg = 0; reg < 4; ++reg)
                        pq[(16 + reg) * PK] = f2bf(d1[reg]);
                }
            }
        }
        __syncthreads();   // Pt complete for this c-quarter

        #pragma unroll
        for (int k = 0; k < KTOT; ++k) {
            int ktg = k * 4 + ktc;
            bf16x8 a = *(const bf16x8*)&Pt[c16 * PQ + k * PK + quad * 8];
            int nt = (k < KMINI) ? w : 4 + w;
            bf16x8 b = *(const bf16x8*)&wswz[((size_t)(ktg * 8 + nt) << 9) + l * 8];
            if (k < KMINI) accY1 = __builtin_amdgcn_mfma_f32_16x16x32_bf16(a, b, accY1, 0, 0, 0);
            else           accY2 = __builtin_amdgcn_mfma_f32_16x16x32_bf16(a, b, accY2, 0, 0, 0);
        }
        __syncthreads();
    }

    // epilogue: store y + fused segment stats
    const int len0 = stacklen[0];
    const bool all0 = (n0 + 15 < len0);
    const bool all1 = (n0 >= len0);
    const int ch = w * 16 + c16;
    #pragma unroll
    for (int half = 0; half < 2; ++half) {
        f32x4 acc = half ? accY2 : accY1;
        float* yb = half ? y2 : y1;
        const int sbase = half ? 256 : 0;
        float s0 = 0.f, q0 = 0.f, s1 = 0.f, q1 = 0.f;
        #pragma unroll
        for (int reg = 0; reg < 4; ++reg) {
            int row = n0 + quad * 4 + reg;
            float v = acc[reg];
            yb[(size_t)row * DH + ch] = v;
            if (row < len0) { s0 += v; q0 += v * v; }
            else            { s1 += v; q1 += v * v; }
        }
        s0 += __shfl_xor(s0, 16); s0 += __shfl_xor(s0, 32);
        q0 += __shfl_xor(q0, 16); q0 += __shfl_xor(q0, 32);
        s1 += __shfl_xor(s1, 16); s1 += __shfl_xor(s1, 32);
        q1 += __shfl_xor(q1, 16); q1 += __shfl_xor(q1, 32);
        if (quad == 0) {
            if (!all1) {
                atomicAdd(&segsum[sbase + 0 * 64 + ch], s0);
                atomicAdd(&segsum[sbase + 1 * 64 + ch], q0);
            }
            if (!all0) {
                atomicAdd(&segsum[sbase + 2 * 64 + ch], s1);
                atomicAdd(&segsum[sbase + 3 * 64 + ch], q1);
            }
        }
    }
}

// -------- kernel T: fused tail GEMM (norm folded into A) + BN partials --------
__global__ __launch_bounds__(128) void k_tailmm(
    const float* __restrict__ y1, const float* __restrict__ y2,
    const float* __restrict__ segsum, const int* __restrict__ stacklen,
    const unsigned short* __restrict__ cfrag,
    float* __restrict__ outpre, float* __restrict__ bnsum, float* __restrict__ bnsq)
{
    __shared__ __align__(16) unsigned short alds[32 * 136];
    __shared__ float sstat[4][2][64];
    const int t = threadIdx.x;
    const int mb = blockIdx.x * 32;
    const int len0 = stacklen[0];

    for (int tt = t; tt < 256; tt += 128) {
        int combo = tt >> 6, ch = tt & 63;
        float cnt = (float)max((combo & 1) ? (NQ - len0) : len0, 1);
        float S = segsum[(combo * 2 + 0) * 64 + ch];
        float Q = segsum[(combo * 2 + 1) * 64 + ch];
        float mean = S / cnt;
        float var = Q / cnt - mean * mean;
        sstat[combo][0][ch] = mean;
        sstat[combo][1][ch] = rsqrtf(fmaxf(var, 0.f) + EPSN);
    }
    __syncthreads();

    for (int tt = t; tt < 32 * 32; tt += 128) {
        int r = tt >> 5, c4 = tt & 31;
        int n = mb + r;
        us4 v4 = (us4){0, 0, 0, 0};
        if (n < NQ) {
            int s = (n >= len0) ? 1 : 0;
            int c = c4 * 4;
            if (c < 64) {
                float4 yv = *(const float4*)&y1[(size_t)n * DH + c];
                v4[0] = f2bf((yv.x - sstat[s][0][c + 0]) * sstat[s][1][c + 0]);
                v4[1] = f2bf((yv.y - sstat[s][0][c + 1]) * sstat[s][1][c + 1]);
                v4[2] = f2bf((yv.z - sstat[s][0][c + 2]) * sstat[s][1][c + 2]);
                v4[3] = f2bf((yv.w - sstat[s][0][c + 3]) * sstat[s][1][c + 3]);
            } else {
                int c2 = c - 64;
                float4 yv = *(const float4*)&y2[(size_t)n * DH + c2];
                v4[0] = f2bf((yv.x - sstat[2 + s][0][c2 + 0]) * sstat[2 + s][1][c2 + 0]);
                v4[1] = f2bf((yv.y - sstat[2 + s][0][c2 + 1]) * sstat[2 + s][1][c2 + 1]);
                v4[2] = f2bf((yv.z - sstat[2 + s][0][c2 + 2]) * sstat[2 + s][1][c2 + 2]);
                v4[3] = f2bf((yv.w - sstat[2 + s][0][c2 + 3]) * sstat[2 + s][1][c2 + 3]);
            }
        }
        *(us4*)(alds + r * 136 + c4 * 4) = v4;
    }
    __syncthreads();

    const int l = t & 63, w = t >> 6;
    f32x4 acc[8];
    #pragma unroll
    for (int q = 0; q < 8; ++q) acc[q] = (f32x4){0.f, 0.f, 0.f, 0.f};

    const unsigned short* ap = alds + (w * 16 + (l & 15)) * 136 + ((l >> 4) << 3);
    const unsigned short* bp = cfrag + l * 8;
    #pragma unroll
    for (int kt = 0; kt < 4; ++kt) {
        bf16x8 a = *(const bf16x8*)(ap + kt * 32);
        #pragma unroll
        for (int nt = 0; nt < 8; ++nt) {
            bf16x8 b = *(const bf16x8*)(bp + (size_t)((kt * 8 + nt) << 9));
            acc[nt] = __builtin_amdgcn_mfma_f32_16x16x32_bf16(a, b, acc[nt], 0, 0, 0);
        }
    }

    const int quad = l >> 4, c16 = l & 15;
    #pragma unroll
    for (int nt = 0; nt < 8; ++nt) {
        float s = 0.f, q = 0.f;
        #pragma unroll
        for (int reg = 0; reg < 4; ++reg) {
            int row = mb + w * 16 + quad * 4 + reg;
            float v = acc[nt][reg];
            if (row < NQ) outpre[(size_t)row * CH + nt * 16 + c16] = v;
            else v = 0.f;
            s += v; q += v * v;
        }
        s += __shfl_xor(s, 16); s += __shfl_xor(s, 32);
        q += __shfl_xor(q, 16); q += __shfl_xor(q, 32);
        if (quad == 0) {
            atomicAdd(&bnsum[nt * 16 + c16], s);
            atomicAdd(&bnsq[nt * 16 + c16], q);
        }
    }
}

// ---------------- FALLBACK kernels (ws too small) -----------------------------
__global__ __launch_bounds__(256) void k_kpconv(
    const float* __restrict__ q_pts, const float* __restrict__ s_pts,
    const int* __restrict__ inds, const float* __restrict__ x,
    const float* __restrict__ kp_mini, const float* __restrict__ kp_mid,
    const float* __restrict__ w_mini, const float* __restrict__ w_mid,
    const float* __restrict__ rowsum,
    float* __restrict__ y1, float* __restrict__ y2)
{
    __shared__ __align__(16) float kpts[KTOT][3];
    __shared__ __align__(16) float nb[128][3];
    __shared__ int   nidx[128];
    __shared__ int   vcnt[4];
    __shared__ float winv[4];
    __shared__ __align__(16) float wts[4][HN][KTOT];
    __shared__ __align__(16) float wt[KTOT][CH][4];
    __shared__ __align__(16) float part[128][4];

    const int t = threadIdx.x;
    const int n0 = blockIdx.x * 4;

    if (t < KTOT * 3) {
        int k = t / 3, j = t % 3;
        kpts[k][j] = (k < KMINI) ? kp_mini[k * 3 + j] : kp_mid[(k - KMINI) * 3 + j];
    }
    if (t < 4) vcnt[t] = 0;
    __syncthreads();

    if (t < 128) {
        int r = t >> 5, h = t & 31;
        int n = n0 + r;
        int idx = inds[n * HN + h];
        nidx[t] = idx;
        float qx = q_pts[n * 3 + 0], qy = q_pts[n * 3 + 1], qz = q_pts[n * 3 + 2];
        nb[t][0] = s_pts[idx * 3 + 0] - qx;
        nb[t][1] = s_pts[idx * 3 + 1] - qy;
        nb[t][2] = s_pts[idx * 3 + 2] - qz;
        if (rowsum[idx] > 0.0f) atomicAdd(&vcnt[r], 1);
    }
    __syncthreads();
    if (t < 4) winv[t] = 1.0f / (float)max(vcnt[t], 1);
    __syncthreads();

    for (int tt = t; tt < 4 * HN * KTOT; tt += 256) {
        int r = tt / (HN * KTOT);
        int rem = tt % (HN * KTOT);
        int h = rem / KTOT, k = rem % KTOT;
        float dx = nb[r * HN + h][0] - kpts[k][0];
        float dy = nb[r * HN + h][1] - kpts[k][1];
        float dz = nb[r * HN + h][2] - kpts[k][2];
        float sq = dx * dx + dy * dy + dz * dz;
        float dist = sqrtf(fmaxf(sq, 1e-12f));
        float w = fmaxf(1.0f - dist * (1.0f / 0.6f), 0.0f);
        wts[r][h][k] = w * winv[r];
    }
    __syncthreads();

    {
        const int g = t >> 7;
        const int c = t & 127;
        for (int rr = 0; rr < 2; ++rr) {
            const int r = g + rr * 2;
            float acc[KTOT];
            #pragma unroll
            for (int k = 0; k < KTOT; ++k) acc[k] = 0.0f;
            for (int h = 0; h < HN; ++h) {
                int idx = nidx[r * HN + h];
                float xv = x[(size_t)idx * CH + c];
                const float4* wp = (const float4*)&wts[r][h][0];
                float4 wa = wp[0], wb = wp[1], wc = wp[2], wd = wp[3], we = wp[4];
                acc[0]  += wa.x * xv; acc[1]  += wa.y * xv; acc[2]  += wa.z * xv; acc[3]  += wa.w * xv;
                acc[4]  += wb.x * xv; acc[5]  += wb.y * xv; acc[6]  += wb.z * xv; acc[7]  += wb.w * xv;
                acc[8]  += wc.x * xv; acc[9]  += wc.y * xv; acc[10] += wc.z * xv; acc[11] += wc.w * xv;
                acc[12] += wd.x * xv; acc[13] += wd.y * xv; acc[14] += wd.z * xv; acc[15] += wd.w * xv;
                acc[16] += we.x * xv; acc[17] += we.y * xv; acc[18] += we.z * xv; acc[19] += we.w * xv;
            }
            #pragma unroll
            for (int k = 0; k < KTOT; ++k) wt[k][c][r] = acc[k];
        }
    }
    __syncthreads();

    {
        const int d = t & 127;
        const int half = t >> 7;
        const int c0 = half * 64;
        float o0 = 0.f, o1 = 0.f, o2 = 0.f, o3 = 0.f;
        if (d < DH) {
            for (int k = 0; k < KMINI; ++k) {
                const float* wp = &w_mini[((size_t)k * CH + c0) * DH + d];
                for (int c = c0; c < c0 + 64; ++c) {
                    float wv = *wp; wp += DH;
                    const float4 wtv = *(const float4*)&wt[k][c][0];
                    o0 += wv * wtv.x; o1 += wv * wtv.y; o2 += wv * wtv.z; o3 += wv * wtv.w;
                }
            }
        } else {
            const int dd = d - DH;
            for (int k = KMINI; k < KTOT; ++k) {
                const float* wp = &w_mid[((size_t)(k - KMINI) * CH + c0) * DH + dd];
                for (int c = c0; c < c0 + 64; ++c) {
                    float wv = *wp; wp += DH;
                    const float4 wtv = *(const float4*)&wt[k][c][0];
                    o0 += wv * wtv.x; o1 += wv * wtv.y; o2 += wv * wtv.z; o3 += wv * wtv.w;
                }
            }
        }
        if (half == 1) { part[d][0] = o0; part[d][1] = o1; part[d][2] = o2; part[d][3] = o3; }
        __syncthreads();
        if (half == 0) {
            o0 += part[d][0]; o1 += part[d][1]; o2 += part[d][2]; o3 += part[d][3];
            if (d < DH) {
                y1[(size_t)(n0 + 0) * DH + d] = o0;
                y1[(size_t)(n0 + 1) * DH + d] = o1;
                y1[(size_t)(n0 + 2) * DH + d] = o2;
                y1[(size_t)(n0 + 3) * DH + d] = o3;
            } else {
                const int dd = d - DH;
                y2[(size_t)(n0 + 0) * DH + dd] = o0;
                y2[(size_t)(n0 + 1) * DH + dd] = o1;
                y2[(size_t)(n0 + 2) * DH + dd] = o2;
                y2[(size_t)(n0 + 3) * DH + dd] = o3;
            }
        }
    }
}

__global__ __launch_bounds__(256) void k_segpart(
    const float* __restrict__ y1, const float* __restrict__ y2,
    const int* __restrict__ stacklen, float* __restrict__ segsum)
{
    const int t = threadIdx.x;
    const int ch = t & 63, grp = t >> 6;
    const int len0 = stacklen[0];
    float a0 = 0.f, a1 = 0.f, a2 = 0.f, a3 = 0.f;
    float b0 = 0.f, b1 = 0.f, b2 = 0.f, b3 = 0.f;
    for (int r = blockIdx.x * 4 + grp; r < NQ; r += 256 * 4) {
        float v1 = y1[(size_t)r * DH + ch];
        float v2 = y2[(size_t)r * DH + ch];
        bool in1 = (r >= len0);
        float m0 = in1 ? 0.f : 1.f, m1 = 1.f - m0;
        a0 += m0 * v1; a1 += m0 * v1 * v1; a2 += m1 * v1; a3 += m1 * v1 * v1;
        b0 += m0 * v2; b1 += m0 * v2 * v2; b2 += m1 * v2; b3 += m1 * v2 * v2;
    }
    __shared__ float red[4][8][64];
    red[grp][0][ch] = a0; red[grp][1][ch] = a1; red[grp][2][ch] = a2; red[grp][3][ch] = a3;
    red[grp][4][ch] = b0; red[grp][5][ch] = b1; red[grp][6][ch] = b2; red[grp][7][ch] = b3;
    __syncthreads();
    for (int tt = t; tt < 512; tt += 256) {
        int j = tt >> 6, c = tt & 63;
        float s = red[0][j][c] + red[1][j][c] + red[2][j][c] + red[3][j][c];
        atomicAdd(&segsum[j * 64 + c], s);
    }
}

__global__ __launch_bounds__(256) void k_tail(
    const float* __restrict__ y1, const float* __restrict__ y2,
    const float* __restrict__ segsum, const int* __restrict__ stacklen,
    const float* __restrict__ w_midmini, const float* __restrict__ w_final,
    float* __restrict__ outpre, float* __restrict__ bnsum, float* __restrict__ bnsq)
{
    __shared__ __align__(16) float sstat[4][2][64];
    __shared__ __align__(16) float sbuf[8][64];
    __shared__ __align__(16) float xc[8][128];
    __shared__ float lsum[2][128], lsq[2][128];
    const int n0 = blockIdx.x * 8;
    const int t = threadIdx.x;
    const int len0 = stacklen[0];

    {
        int combo = t >> 6, ch = t & 63;
        float cnt = (float)max((combo & 1) ? (NQ - len0) : len0, 1);
        float S = segsum[(combo * 2 + 0) * 64 + ch];
        float Q = segsum[(combo * 2 + 1) * 64 + ch];
        float mean = S / cnt;
        float var = Q / cnt - mean * mean;
        sstat[combo][0][ch] = mean;
        sstat[combo][1][ch] = rsqrtf(fmaxf(var, 0.f) + EPSN);
    }
    __syncthreads();

    for (int tt = t; tt < 8 * 64; tt += 256) {
        int r = tt >> 6, d = tt & 63;
        int n = n0 + r;
        int s = (n >= len0) ? 1 : 0;
        float x1n = (y1[(size_t)n * DH + d] - sstat[s][0][d]) * sstat[s][1][d];
        float x2n = (y2[(size_t)n * DH + d] - sstat[2 + s][0][d]) * sstat[2 + s][1][d];
        xc[r][d] = x1n;
        sbuf[r][d] = x1n + x2n;
    }
    __syncthreads();

    for (int tt = t; tt < 8 * 64; tt += 256) {
        int r = tt >> 6, d = tt & 63;
        float a = 0.f;
        const float4* wmr = (const float4*)&w_midmini[(size_t)d * 64];
        const float4* sv = (const float4*)&sbuf[r][0];
        #pragma unroll
        for (int e4 = 0; e4 < 16; ++e4) {
            float4 w4 = wmr[e4], s4 = sv[e4];
            a += w4.x * s4.x + w4.y * s4.y + w4.z * s4.z + w4.w * s4.w;
        }
        xc[r][64 + d] = a;
    }
    __syncthreads();

    {
        const int j = t & 127;
        const int g = t >> 7;
        float o0 = 0.f, o1 = 0.f, o2 = 0.f, o3 = 0.f;
        const float4* wfr = (const float4*)&w_final[(size_t)j * 128];
        #pragma unroll 8
        for (int i4 = 0; i4 < 32; ++i4) {
            float4 wf = wfr[i4];
            float4 a0 = *(const float4*)&xc[g + 0][i4 * 4];
            float4 a1 = *(const float4*)&xc[g + 2][i4 * 4];
            float4 a2 = *(const float4*)&xc[g + 4][i4 * 4];
            float4 a3 = *(const float4*)&xc[g + 6][i4 * 4];
            o0 += wf.x * a0.x + wf.y * a0.y + wf.z * a0.z + wf.w * a0.w;
            o1 += wf.x * a1.x + wf.y * a1.y + wf.z * a1.z + wf.w * a1.w;
            o2 += wf.x * a2.x + wf.y * a2.y + wf.z * a2.z + wf.w * a2.w;
            o3 += wf.x * a3.x + wf.y * a3.y + wf.z * a3.z + wf.w * a3.w;
        }
        outpre[(size_t)(n0 + g + 0) * CH + j] = o0;
        outpre[(size_t)(n0 + g + 2) * CH + j] = o1;
        outpre[(size_t)(n0 + g + 4) * CH + j] = o2;
        outpre[(size_t)(n0 + g + 6) * CH + j] = o3;
        lsum[g][j] = o0 + o1 + o2 + o3;
        lsq[g][j]  = o0 * o0 + o1 * o1 + o2 * o2 + o3 * o3;
        __syncthreads();
        if (g == 0) {
            atomicAdd(&bnsum[j], lsum[0][j] + lsum[1][j]);
            atomicAdd(&bnsq[j],  lsq[0][j] + lsq[1][j]);
        }
    }
}

// ---------------- kernel 5: BN apply + relu ----------------------------------
__global__ __launch_bounds__(256) void k_bnapply(const float* __restrict__ outpre,
    const float* __restrict__ bnsum, const float* __restrict__ bnsq,
    const float* __restrict__ gamma, const float* __restrict__ beta,
    float* __restrict__ out)
{
    int e4 = blockIdx.x * 256 + threadIdx.x;
    if (e4 >= NQ * CH / 4) return;
    int j0 = (e4 * 4) & 127;
    float4 v = ((const float4*)outpre)[e4];
    float vv[4] = {v.x, v.y, v.z, v.w};
    float res[4];
    #pragma unroll
    for (int i = 0; i < 4; ++i) {
        int j = j0 + i;
        float mean = bnsum[j] * (1.0f / NQ);
        float var = bnsq[j] * (1.0f / NQ) - mean * mean;
        float rstd = rsqrtf(fmaxf(var, 0.f) + EPSN);
        float r = (vv[i] - mean) * rstd * gamma[j] + beta[j];
        res[i] = fmaxf(r, 0.f);
    }
    ((float4*)out)[e4] = make_float4(res[0], res[1], res[2], res[3]);
}

extern "C" void kernel_launch(void* const* d_in, const int* in_sizes, int n_in,
                              void* d_out, int out_size, void* d_ws, size_t ws_size,
                              hipStream_t stream) {
    const float* q_pts     = (const float*)d_in[0];
    const float* s_pts     = (const float*)d_in[1];
    const int*   inds      = (const int*)d_in[2];
    const float* x         = (const float*)d_in[3];
    const int*   stacklen  = (const int*)d_in[4];
    const float* kp_mini   = (const float*)d_in[5];
    const float* w_mini    = (const float*)d_in[6];
    const float* kp_mid    = (const float*)d_in[7];
    const float* w_mid     = (const float*)d_in[8];
    const float* w_midmini = (const float*)d_in[9];
    const float* w_final   = (const float*)d_in[10];
    const float* gamma     = (const float*)d_in[11];
    const float* beta      = (const float*)d_in[12];

    float* ws      = (float*)d_ws;
    float* rowsum  = ws + OFF_ROWSUM;
    float* y1      = ws + OFF_Y1;
    float* y2      = ws + OFF_Y2;
    float* segsum  = ws + OFF_SEGSUM;
    float* bnsum   = ws + OFF_BNSUM;
    float* bnsq    = ws + OFF_BNSQ;
    float* outpre  = ws + OFF_OUTPRE;
    unsigned short* wswz  = (unsigned short*)(ws + OFF_WSWZ);
    unsigned short* cfrag = (unsigned short*)(ws + OFF_CFRAG);
    unsigned short* x_bf  = (unsigned short*)(ws + OFF_XBF);

    hipMemsetAsync(segsum, 0, 768 * sizeof(float), stream);

    if (ws_size >= (size_t)TOT_FLOATS * sizeof(float)) {
        k_prep<<<1250 + 1280 + 32, 256, 0, stream>>>(x, rowsum, w_mini, w_mid,
                                                     w_midmini, w_final, wswz, cfrag, x_bf);
        k_fused2<<<NQ / 16, 256, 0, stream>>>(q_pts, s_pts, inds, x_bf, kp_mini, kp_mid,
                                              rowsum, wswz, stacklen, y1, y2, segsum);
        k_tailmm<<<(NQ + 31) / 32, 128, 0, stream>>>(y1, y2, segsum, stacklen, cfrag,
                                                     outpre, bnsum, bnsq);
    } else {
        k_prep<<<1250, 256, 0, stream>>>(x, rowsum, w_mini, w_mid,
                                         w_midmini, w_final, wswz, cfrag, (unsigned short*)0);
        k_kpconv<<<NQ / 4, 256, 0, stream>>>(q_pts, s_pts, inds, x, kp_mini, kp_mid,
                                             w_mini, w_mid, rowsum, y1, y2);
        k_segpart<<<256, 256, 0, stream>>>(y1, y2, stacklen, segsum);
        k_tail<<<NQ / 8, 256, 0, stream>>>(y1, y2, segsum, stacklen, w_midmini, w_final,
                                           outpre, bnsum, bnsq);
    }

    k_bnapply<<<(NQ * CH / 4 + 255) / 256, 256, 0, stream>>>(outpre, bnsum, bnsq,
                                                             gamma, beta, (float*)d_out);
}